// Round 1
// baseline (18819.214 us; speedup 1.0000x reference)
//
#include <hip/hip_runtime.h>
#include <hip/hip_bf16.h>
#include <cstdint>
#include <cstddef>

#define BB 64
#define TT 512
#define DD 1024
#define HH 2048
#define GG 8192   // 4*H
#define KK 3072   // D+H

typedef unsigned short u16;
typedef __attribute__((ext_vector_type(8))) short bf16x8;
typedef __attribute__((ext_vector_type(4))) float f32x4;

__device__ __forceinline__ u16 f2bf(float f) {
  union { float f; uint32_t u; } v; v.f = f;
  uint32_t r = v.u + 0x7FFFu + ((v.u >> 16) & 1u);  // RNE
  return (u16)(r >> 16);
}

__device__ __forceinline__ bf16x8 cvt8(const float* __restrict__ p) {
  float4 a = *(const float4*)p;
  float4 b = *(const float4*)(p + 4);
  bf16x8 r;
  r[0] = (short)f2bf(a.x); r[1] = (short)f2bf(a.y);
  r[2] = (short)f2bf(a.z); r[3] = (short)f2bf(a.w);
  r[4] = (short)f2bf(b.x); r[5] = (short)f2bf(b.y);
  r[6] = (short)f2bf(b.z); r[7] = (short)f2bf(b.w);
  return r;
}

// ---- prep: convert [W_ih | W_hh] rows into combined bf16 Wc[G][K] ----
__global__ void conv_w_kernel(const float* __restrict__ W_ih,
                              const float* __restrict__ W_hh,
                              u16* __restrict__ Wc) {
  size_t idx = (size_t)blockIdx.x * blockDim.x + threadIdx.x;
  if (idx >= (size_t)GG * KK / 8) return;
  size_t e = idx * 8;
  int r = (int)(e / KK);
  int k = (int)(e % KK);
  bf16x8 v;
  if (k < DD) v = cvt8(W_ih + (size_t)r * DD + k);
  else        v = cvt8(W_hh + (size_t)r * HH + (k - DD));
  *(bf16x8*)(Wc + e) = v;
}

__global__ void conv_x_kernel(const float* __restrict__ x, u16* __restrict__ xb) {
  size_t idx = (size_t)blockIdx.x * blockDim.x + threadIdx.x;
  if (idx >= (size_t)BB * TT * DD / 8) return;
  size_t e = idx * 8;
  *(bf16x8*)(xb + e) = cvt8(x + e);
}

// ---- one LSTM timestep ----
// grid: 256 WGs x 512 thr. WG owns 8 h-indices j0..j0+7 => gate rows
// {i,f} in tile0, {g,o} in tile1. 8 waves: m-tile = wave&3, k-half = wave>>2.
template<int MODE>   // 2: bf16 x + bf16 W; 1: fp32 x + bf16 W; 0: all fp32 sources
__global__ __launch_bounds__(512)
void lstm_step_kernel(const float* __restrict__ x, const u16* __restrict__ xb,
                      const float* __restrict__ W_ih, const float* __restrict__ W_hh,
                      const u16* __restrict__ Wc,
                      const float* __restrict__ b_ih, const float* __restrict__ b_hh,
                      const u16* __restrict__ h_src, u16* __restrict__ h_dst,
                      float* __restrict__ cbuf, int t) {
  const int tid = threadIdx.x;
  const int wave = tid >> 6, lane = tid & 63;
  const int m = wave & 3, khalf = wave >> 2;
  const int j0 = blockIdx.x * 8;
  const int c = lane & 15;
  const int arow = m * 16 + c;            // A (batch) row for fragment load
  const int koff = (lane >> 4) * 8;       // k sub-offset within 32-wide step
  const int r0 = (c < 8) ? (j0 + c) : (HH + j0 + c - 8);          // i | f rows
  const int r1 = (c < 8) ? (2 * HH + j0 + c) : (3 * HH + j0 + c - 8); // g | o rows

  f32x4 acc0 = {0.f, 0.f, 0.f, 0.f};
  f32x4 acc1 = {0.f, 0.f, 0.f, 0.f};

  if (khalf == 0) {
    // x part: k in [0, 1024)
    const size_t xrow = ((size_t)arow * TT + t) * DD;
    #pragma unroll 4
    for (int kb = 0; kb < 32; ++kb) {
      const int k = kb * 32 + koff;
      bf16x8 a;
      if constexpr (MODE == 2) a = *(const bf16x8*)(xb + xrow + k);
      else                     a = cvt8(x + xrow + k);
      bf16x8 b0, b1;
      if constexpr (MODE >= 1) {
        b0 = *(const bf16x8*)(Wc + (size_t)r0 * KK + k);
        b1 = *(const bf16x8*)(Wc + (size_t)r1 * KK + k);
      } else {
        b0 = cvt8(W_ih + (size_t)r0 * DD + k);
        b1 = cvt8(W_ih + (size_t)r1 * DD + k);
      }
      acc0 = __builtin_amdgcn_mfma_f32_16x16x32_bf16(a, b0, acc0, 0, 0, 0);
      acc1 = __builtin_amdgcn_mfma_f32_16x16x32_bf16(a, b1, acc1, 0, 0, 0);
    }
    // h part: k in [1024, 1536) -> kh in [0, 512)
    #pragma unroll 4
    for (int kb = 0; kb < 16; ++kb) {
      const int kh = kb * 32 + koff;
      bf16x8 a = *(const bf16x8*)(h_src + (size_t)arow * HH + kh);
      bf16x8 b0, b1;
      if constexpr (MODE >= 1) {
        b0 = *(const bf16x8*)(Wc + (size_t)r0 * KK + DD + kh);
        b1 = *(const bf16x8*)(Wc + (size_t)r1 * KK + DD + kh);
      } else {
        b0 = cvt8(W_hh + (size_t)r0 * HH + kh);
        b1 = cvt8(W_hh + (size_t)r1 * HH + kh);
      }
      acc0 = __builtin_amdgcn_mfma_f32_16x16x32_bf16(a, b0, acc0, 0, 0, 0);
      acc1 = __builtin_amdgcn_mfma_f32_16x16x32_bf16(a, b1, acc1, 0, 0, 0);
    }
  } else {
    // k in [1536, 3072) -> kh in [512, 2048)
    #pragma unroll 4
    for (int kb = 0; kb < 48; ++kb) {
      const int kh = 512 + kb * 32 + koff;
      bf16x8 a = *(const bf16x8*)(h_src + (size_t)arow * HH + kh);
      bf16x8 b0, b1;
      if constexpr (MODE >= 1) {
        b0 = *(const bf16x8*)(Wc + (size_t)r0 * KK + DD + kh);
        b1 = *(const bf16x8*)(Wc + (size_t)r1 * KK + DD + kh);
      } else {
        b0 = cvt8(W_hh + (size_t)r0 * HH + kh);
        b1 = cvt8(W_hh + (size_t)r1 * HH + kh);
      }
      acc0 = __builtin_amdgcn_mfma_f32_16x16x32_bf16(a, b0, acc0, 0, 0, 0);
      acc1 = __builtin_amdgcn_mfma_f32_16x16x32_bf16(a, b1, acc1, 0, 0, 0);
    }
  }

  // reduce k-halves across wave pairs via LDS
  __shared__ float red[4][2][64][4];
  if (khalf == 1) {
    #pragma unroll
    for (int q = 0; q < 4; ++q) { red[m][0][lane][q] = acc0[q]; red[m][1][lane][q] = acc1[q]; }
  }
  __syncthreads();
  if (khalf == 1) return;
  #pragma unroll
  for (int q = 0; q < 4; ++q) { acc0[q] += red[m][0][lane][q]; acc1[q] += red[m][1][lane][q]; }

  // biases (b_ih + b_hh), per gate row
  const float bias0 = b_ih[r0] + b_hh[r0];
  const float bias1 = b_ih[r1] + b_hh[r1];
  #pragma unroll
  for (int q = 0; q < 4; ++q) { acc0[q] += bias0; acc1[q] += bias1; }

  // lanes c<8 hold i (acc0) and g (acc1); partners at lane^8 hold f and o
  float fpre[4], opre[4];
  #pragma unroll
  for (int q = 0; q < 4; ++q) {
    fpre[q] = __shfl_xor(acc0[q], 8);
    opre[q] = __shfl_xor(acc1[q], 8);
  }

  if (c < 8) {
    const int j = j0 + c;
    #pragma unroll
    for (int q = 0; q < 4; ++q) {
      const int b = m * 16 + (lane >> 4) * 4 + q;   // C-layout row
      const float ig = 1.f / (1.f + expf(-acc0[q]));
      const float fg = 1.f / (1.f + expf(-fpre[q]));
      const float gg = tanhf(acc1[q]);
      const float og = 1.f / (1.f + expf(-opre[q]));
      const float cold = cbuf[(size_t)b * HH + j];
      const float cn = fg * cold + ig * gg;
      cbuf[(size_t)b * HH + j] = cn;
      h_dst[(size_t)b * HH + j] = f2bf(og * tanhf(cn));
    }
  }
}

// ---- head: out[b][d] = h_final @ W_head^T + b_head ----
__global__ __launch_bounds__(256)
void head_kernel(const u16* __restrict__ hfin, const float* __restrict__ W_head,
                 const float* __restrict__ b_head, float* __restrict__ out) {
  const int tid = threadIdx.x, wave = tid >> 6, lane = tid & 63;
  const int m = wave;
  const int c = lane & 15;
  const int koff = (lane >> 4) * 8;
  const int d = blockIdx.x * 16 + c;
  const int arow = m * 16 + c;
  f32x4 acc = {0.f, 0.f, 0.f, 0.f};
  #pragma unroll 4
  for (int kb = 0; kb < 64; ++kb) {
    const int k = kb * 32 + koff;
    bf16x8 a = *(const bf16x8*)(hfin + (size_t)arow * HH + k);
    bf16x8 b = cvt8(W_head + (size_t)d * HH + k);
    acc = __builtin_amdgcn_mfma_f32_16x16x32_bf16(a, b, acc, 0, 0, 0);
  }
  const float bh = b_head[d];
  #pragma unroll
  for (int q = 0; q < 4; ++q) {
    const int b = m * 16 + (lane >> 4) * 4 + q;
    out[(size_t)b * DD + d] = acc[q] + bh;
  }
}

extern "C" void kernel_launch(void* const* d_in, const int* in_sizes, int n_in,
                              void* d_out, int out_size, void* d_ws, size_t ws_size,
                              hipStream_t stream) {
  const float* x      = (const float*)d_in[0];
  const float* W_ih   = (const float*)d_in[1];
  const float* W_hh   = (const float*)d_in[2];
  const float* b_ih   = (const float*)d_in[3];
  const float* b_hh   = (const float*)d_in[4];
  const float* W_head = (const float*)d_in[5];
  const float* b_head = (const float*)d_in[6];
  float* out = (float*)d_out;

  char* ws = (char*)d_ws;
  const size_t OFF_H0 = 0;
  const size_t OFF_H1 = (size_t)BB * HH * 2;            // 256 KB
  const size_t OFF_C  = OFF_H1 + (size_t)BB * HH * 2;   // 512 KB
  const size_t OFF_W  = 1u << 20;                       // 1 MB
  const size_t SZ_W   = (size_t)GG * KK * 2;            // 48 MB
  const size_t OFF_X  = OFF_W + SZ_W;
  const size_t SZ_X   = (size_t)BB * TT * DD * 2;       // 64 MB

  int mode = 0;
  if (ws_size >= OFF_X + SZ_X)      mode = 2;
  else if (ws_size >= OFF_W + SZ_W) mode = 1;

  u16*  h0   = (u16*)(ws + OFF_H0);
  u16*  h1   = (u16*)(ws + OFF_H1);
  float* cbuf = (float*)(ws + OFF_C);
  u16*  Wc   = (u16*)(ws + OFF_W);
  u16*  xb   = (u16*)(ws + OFF_X);

  // zero h ping-pong + c (poisoned between runs)
  hipMemsetAsync(ws, 0, 1u << 20, stream);

  if (mode >= 1) {
    const int n8 = (int)((size_t)GG * KK / 8);
    conv_w_kernel<<<(n8 + 255) / 256, 256, 0, stream>>>(W_ih, W_hh, Wc);
  }
  if (mode == 2) {
    const int n8 = (int)((size_t)BB * TT * DD / 8);
    conv_x_kernel<<<(n8 + 255) / 256, 256, 0, stream>>>(x, xb);
  }

  for (int t = 0; t < TT; ++t) {
    u16* hs = (t & 1) ? h1 : h0;
    u16* hd = (t & 1) ? h0 : h1;
    if (mode == 2)
      lstm_step_kernel<2><<<256, 512, 0, stream>>>(x, xb, W_ih, W_hh, Wc, b_ih, b_hh, hs, hd, cbuf, t);
    else if (mode == 1)
      lstm_step_kernel<1><<<256, 512, 0, stream>>>(x, xb, W_ih, W_hh, Wc, b_ih, b_hh, hs, hd, cbuf, t);
    else
      lstm_step_kernel<0><<<256, 512, 0, stream>>>(x, xb, W_ih, W_hh, Wc, b_ih, b_hh, hs, hd, cbuf, t);
  }

  // after t=511 (odd), final h is in h0
  head_kernel<<<64, 256, 0, stream>>>(h0, W_head, b_head, out);
}